// Round 3
// baseline (6939.325 us; speedup 1.0000x reference)
//
#include <hip/hip_runtime.h>
#include <hip/hip_bf16.h>

// MHAHead: B=8, S=2048, E=512, single head.
// q = x@wq^T+bq ; k,v likewise ; s = q.k^T*E^-0.5 ; mask>0 -> -inf ; softmax ;
// out = p@v.  Inputs fp32 (runtime-detected, bf16 fallback), output fp32.
//
// Buffers:
//   d_out rows (2048 B each): Q bf16 in leading 1024 B during the pass, then
//     overwritten with the fp32 output row by the SAME block that read it.
//   x rows (fp32 mode, 2048 B): V bf16 -> bytes [0,1024), K bf16 -> [1024,2048).
//   bf16-input mode: V in-place over x rows (1024 B), K -> d_ws.

typedef unsigned short ushort_t;

#define S_DIM 2048
#define E_DIM 512
#define NROWS (8 * S_DIM)

__device__ __forceinline__ float bf2f(unsigned int u) {
    union { unsigned int i; float f; } v; v.i = u << 16; return v.f;
}

__device__ __forceinline__ void cvt8(const uint4 v, float* f) {
    f[0] = bf2f(v.x & 0xffffu); f[1] = bf2f(v.x >> 16);
    f[2] = bf2f(v.y & 0xffffu); f[3] = bf2f(v.y >> 16);
    f[4] = bf2f(v.z & 0xffffu); f[5] = bf2f(v.z >> 16);
    f[6] = bf2f(v.w & 0xffffu); f[7] = bf2f(v.w >> 16);
}

__device__ __forceinline__ ushort_t f2bf_bits(float f) {
    __hip_bfloat16 h = __float2bfloat16(f);
    return *(ushort_t*)&h;
}

// bf16 data -> even 16-bit words have sane exponents (~100%); fp32 data ->
// even words are mantissa halves, exponent field ~uniform (~12.5% plausible).
__device__ __forceinline__ int detect_bf16(const void* wp) {
    const ushort_t* w = (const ushort_t*)wp;
    int cnt = 0;
    for (int i = 0; i < 128; ++i) {
        int e = (w[2 * i] >> 7) & 0xff;
        cnt += (e >= 100 && e <= 131) ? 1 : 0;
    }
    return cnt >= 80;
}

__device__ __forceinline__ void load8(const void* base, size_t idx, int isbf, float* f) {
    if (isbf) {
        uint4 v = *(const uint4*)((const ushort_t*)base + idx);
        cvt8(v, f);
    } else {
        const float* p = (const float*)base + idx;
        float4 a = *(const float4*)p;
        float4 b = *(const float4*)(p + 4);
        f[0] = a.x; f[1] = a.y; f[2] = a.z; f[3] = a.w;
        f[4] = b.x; f[5] = b.y; f[6] = b.z; f[7] = b.w;
    }
}

__device__ __forceinline__ float load1(const void* base, size_t idx, int isbf) {
    return isbf ? bf2f(((const ushort_t*)base)[idx]) : ((const float*)base)[idx];
}

// ---------------- Q projection: out[m][n] = x[m]·w[n] + b[n], bf16 out ------
// grid (4, 128), block 256. Output rows at out + m*out_stride (bytes).
__global__ __launch_bounds__(256) void proj_kernel(
    const void* __restrict__ x, const void* __restrict__ w,
    const void* __restrict__ bias, char* out, size_t out_stride)
{
    __shared__ float As[32][132];
    __shared__ float Bs[32][132];

    const int isbf = detect_bf16(w);
    const int t  = threadIdx.x;
    const int m0 = blockIdx.y * 128;
    const int n0 = blockIdx.x * 128;
    const int tx = t & 15, ty = t >> 4;

    float acc[8][8] = {};
    float bval[8];
#pragma unroll
    for (int j = 0; j < 8; ++j)
        bval[j] = load1(bias, n0 + tx * 8 + j, isbf);

    const int r0 = t >> 2;
    const int c8 = (t & 3) * 8;

    for (int kt = 0; kt < E_DIM; kt += 32) {
#pragma unroll
        for (int half = 0; half < 2; ++half) {
            const int r = r0 + half * 64;
            float fa[8], fb[8];
            load8(x, (size_t)(m0 + r) * E_DIM + kt + c8, isbf, fa);
            load8(w, (size_t)(n0 + r) * E_DIM + kt + c8, isbf, fb);
#pragma unroll
            for (int i = 0; i < 8; ++i) {
                As[c8 + i][r] = fa[i];
                Bs[c8 + i][r] = fb[i];
            }
        }
        __syncthreads();
#pragma unroll
        for (int k = 0; k < 32; ++k) {
            float4 a0 = *(const float4*)&As[k][ty * 8];
            float4 a1 = *(const float4*)&As[k][ty * 8 + 4];
            float4 b0 = *(const float4*)&Bs[k][tx * 8];
            float4 b1 = *(const float4*)&Bs[k][tx * 8 + 4];
            float a[8] = {a0.x, a0.y, a0.z, a0.w, a1.x, a1.y, a1.z, a1.w};
            float b[8] = {b0.x, b0.y, b0.z, b0.w, b1.x, b1.y, b1.z, b1.w};
#pragma unroll
            for (int i = 0; i < 8; ++i)
#pragma unroll
                for (int j = 0; j < 8; ++j) acc[i][j] += a[i] * b[j];
        }
        __syncthreads();
    }

#pragma unroll
    for (int i = 0; i < 8; ++i) {
        ushort_t row[8] __attribute__((aligned(16)));
#pragma unroll
        for (int j = 0; j < 8; ++j)
            row[j] = f2bf_bits(acc[i][j] + bval[j]);
        *(uint4*)(out + (size_t)(m0 + ty * 8 + i) * out_stride +
                  (size_t)(n0 + tx * 8) * 2) = *(const uint4*)row;
    }
}

// ---------------- K+V projection, in-place into the x buffer ----------------
// grid 512, block 256. Each block stages its 32 rows of x to LDS, then writes
// K and V (bf16) over its own rows (fp32 mode) / V over x + K to kws (bf16).
__global__ __launch_bounds__(256) void kv_inplace(
    void* xbuf, const void* __restrict__ wk, const void* __restrict__ bk,
    const void* __restrict__ wv, const void* __restrict__ bv, char* kws)
{
    __shared__ __hip_bfloat16 xs[32][512];

    const int isbf = detect_bf16(wk);
    const int t  = threadIdx.x;
    const int m0 = blockIdx.x * 32;

#pragma unroll
    for (int u = 0; u < 8; ++u) {
        const int g = t + 256 * u;          // 2048 granules of 8 elems
        const int r = g >> 6, c8 = (g & 63) * 8;
        float f[8];
        load8(xbuf, (size_t)(m0 + r) * E_DIM + c8, isbf, f);
#pragma unroll
        for (int i = 0; i < 8; ++i) xs[r][c8 + i] = __float2bfloat16(f[i]);
    }
    __syncthreads();

    const int rt = (t >> 5) * 4;        // 4 rows
    const int ct = (t & 31) * 16;       // 16 cols

    for (int pass = 0; pass < 2; ++pass) {          // 0 = K, 1 = V
        const void* w  = pass ? wv : wk;
        const void* bb = pass ? bv : bk;
        float acc[4][16] = {};

        for (int e8 = 0; e8 < 64; ++e8) {
            float xv4[4][8];
#pragma unroll
            for (int r = 0; r < 4; ++r) {
                uint4 v = *(const uint4*)&xs[rt + r][e8 * 8];
                cvt8(v, xv4[r]);
            }
#pragma unroll
            for (int c = 0; c < 16; ++c) {
                float wf[8];
                load8(w, (size_t)(ct + c) * E_DIM + e8 * 8, isbf, wf);
#pragma unroll
                for (int r = 0; r < 4; ++r)
#pragma unroll
                    for (int j = 0; j < 8; ++j) acc[r][c] += xv4[r][j] * wf[j];
            }
        }

        float bc[16];
#pragma unroll
        for (int c = 0; c < 16; ++c) bc[c] = load1(bb, ct + c, isbf);

#pragma unroll
        for (int r = 0; r < 4; ++r) {
            ushort_t tmp[16] __attribute__((aligned(16)));
#pragma unroll
            for (int c = 0; c < 16; ++c) tmp[c] = f2bf_bits(acc[r][c] + bc[c]);
            const size_t row = (size_t)(m0 + rt + r);
            char* dst;
            if (pass == 0)
                dst = isbf ? (kws + row * 1024 + ct * 2)
                           : ((char*)xbuf + row * 2048 + 1024 + ct * 2);
            else
                dst = (char*)xbuf + row * (isbf ? 1024 : 2048) + ct * 2;
            *(uint4*)dst        = ((const uint4*)tmp)[0];
            *(uint4*)(dst + 16) = ((const uint4*)tmp)[1];
        }
    }
}

// ---------------- attention ----------------
// grid (128, 8), block 256. 16 q-rows/block. Q bf16 from d_out rows (leading
// 1024 B), output fp32 over the same rows at the end.
__global__ __launch_bounds__(256) void attn_kernel(
    const char* qbase,                  // d_out
    const char* xbuf,                   // V (and K in fp32 mode)
    const char* kws,                    // K in bf16-input mode
    const void* __restrict__ wv,        // dtype detection only
    const int* __restrict__ mask,
    float* out)                         // d_out
{
    __shared__ float Qs[16][520];
    __shared__ float Ps[16][256];
    __shared__ float red[16][16];

    const int isbf = detect_bf16(wv);
    const size_t vrow = isbf ? (size_t)1024 : (size_t)2048;   // V byte stride
    const size_t krow = isbf ? (size_t)1024 : (size_t)2048;   // K byte stride
    const size_t koff = isbf ? (size_t)0 : (size_t)1024;

    const int t   = threadIdx.x;
    const int b   = blockIdx.y;
    const int q0  = blockIdx.x * 16;
    const int qi  = t >> 4;
    const int l16 = t & 15;

#pragma unroll
    for (int u = 0; u < 4; ++u) {
        const int g = t + 256 * u;
        const int r = g >> 6, c8 = (g & 63) * 8;
        uint4 v = *(const uint4*)(qbase + (size_t)(b * S_DIM + q0 + r) * 2048 +
                                  (size_t)c8 * 2);
        float f[8]; cvt8(v, f);
#pragma unroll
        for (int i = 0; i < 8; ++i) Qs[r][c8 + i] = f[i];
    }

    float o[32] = {};
    float lacc = 0.f;
    __syncthreads();

    const float scale = 0.044194173824159216f;   // 512^-0.5
    const char* kbase0 = isbf ? kws : xbuf;

    for (int c = 0; c < 8; ++c) {
        const int kb = c * 256;

        // ---- scores: thread (qi,l16) handles 16 consecutive keys ----
        {
            float a2[16] = {};
            const char* kr = kbase0 + (size_t)(b * S_DIM + kb + l16 * 16) * krow + koff;
            for (int e8 = 0; e8 < 64; ++e8) {
                float4 qa = *(const float4*)&Qs[qi][e8 * 8];
                float4 qb = *(const float4*)&Qs[qi][e8 * 8 + 4];
#pragma unroll
                for (int i = 0; i < 16; ++i) {
                    const ushort_t* kp = (const ushort_t*)(kr + (size_t)i * krow) + e8 * 8;
                    uint4 kv = *(const uint4*)kp;
                    float f[8]; cvt8(kv, f);
                    a2[i] += qa.x * f[0] + qa.y * f[1] + qa.z * f[2] + qa.w * f[3]
                           + qb.x * f[4] + qb.y * f[5] + qb.z * f[6] + qb.w * f[7];
                }
            }
            const int* mrow = mask + (size_t)(b * S_DIM + q0 + qi) * S_DIM + kb + l16 * 16;
#pragma unroll
            for (int i = 0; i < 16; ++i) {
                float p = (mrow[i] > 0) ? 0.f : __expf(a2[i] * scale);
                Ps[qi][l16 * 16 + i] = p;
                lacc += p;
            }
        }
        __syncthreads();

        // ---- PV: thread (qi,l16) owns output cols l16*32..+31 ----
        {
            const char* vb = xbuf + (size_t)(b * S_DIM + kb) * vrow + (size_t)l16 * 64;
            for (int j = 0; j < 256; ++j) {
                const float p = Ps[qi][j];
                const ushort_t* vp = (const ushort_t*)(vb + (size_t)j * vrow);
                uint4 v0 = ((const uint4*)vp)[0];
                uint4 v1 = ((const uint4*)vp)[1];
                uint4 v2 = ((const uint4*)vp)[2];
                uint4 v3 = ((const uint4*)vp)[3];
                float f[32];
                cvt8(v0, f); cvt8(v1, f + 8); cvt8(v2, f + 16); cvt8(v3, f + 24);
#pragma unroll
                for (int k = 0; k < 32; ++k) o[k] += p * f[k];
            }
        }
        __syncthreads();
    }

    red[qi][l16] = lacc;
    __syncthreads();
    float rl = 0.f;
#pragma unroll
    for (int j = 0; j < 16; ++j) rl += red[qi][j];
    const float inv = 1.0f / rl;

    float* op = out + (size_t)(b * S_DIM + q0 + qi) * E_DIM + l16 * 32;
#pragma unroll
    for (int k = 0; k < 32; k += 4) {
        float4 v = make_float4(o[k] * inv, o[k + 1] * inv, o[k + 2] * inv, o[k + 3] * inv);
        *(float4*)(op + k) = v;
    }
}

extern "C" void kernel_launch(void* const* d_in, const int* in_sizes, int n_in,
                              void* d_out, int out_size, void* d_ws, size_t ws_size,
                              hipStream_t stream) {
    const void* x    = d_in[0];
    const int*  mask = (const int*)d_in[1];
    const void* wq   = d_in[2];
    const void* bq   = d_in[3];
    const void* wk   = d_in[4];
    const void* bk   = d_in[5];
    const void* wv   = d_in[6];
    const void* bv   = d_in[7];

    char* qbase = (char*)d_out;          // Q bf16 @ stride 2048 B
    char* kws   = (char*)d_ws;           // K (bf16-input mode only)

    dim3 gp(E_DIM / 128, NROWS / 128);
    proj_kernel<<<gp, 256, 0, stream>>>(x, wq, bq, qbase, (size_t)2048);

    kv_inplace<<<NROWS / 32, 256, 0, stream>>>((void*)x, wk, bk, wv, bv, kws);

    dim3 ga(S_DIM / 16, 8);
    attn_kernel<<<ga, 256, 0, stream>>>(qbase, (const char*)x, kws, wv, mask,
                                        (float*)d_out);
}

// Round 4
// 567.329 us; speedup vs baseline: 12.2316x; 12.2316x over previous
//
#include <hip/hip_runtime.h>
#include <hip/hip_bf16.h>

// MHAHead: B=8, S=2048, E=512, single head. MFMA (16x16x32 bf16) version.
// proj: Q -> d_out leading halves (bf16, row stride 2048 B)
//       K -> rows [16384][512] bf16 (d_ws or d_out trailing halves)
//       V -> transposed epilogue: Vt [8][512][2048] bf16 in d_ws
// attn: flash-style, 32 q/block, 64-key chunks, K/Vt frags straight from
//       global, P via double-buffered LDS (C-layout -> A-layout), 1 barrier
//       per chunk, max-free softmax (|scores| <~ 0.5 by construction).

typedef unsigned short u16;
typedef __attribute__((ext_vector_type(8))) short short8;
typedef __attribute__((ext_vector_type(4))) float float4v;

#define S_DIM 2048
#define E_DIM 512
#define NROWS (8 * S_DIM)
#define SCALE 0.044194173824159216f   // 512^-0.5

__device__ __forceinline__ float4v mfma16(short8 a, short8 b, float4v c) {
    return __builtin_amdgcn_mfma_f32_16x16x32_bf16(a, b, c, 0, 0, 0);
}

__device__ __forceinline__ float bf2f(unsigned int u) {
    union { unsigned int i; float f; } v; v.i = u << 16; return v.f;
}
__device__ __forceinline__ u16 f2bf_bits(float f) {
    __hip_bfloat16 h = __float2bfloat16(f);
    return *(u16*)&h;
}

// bf16 data -> even 16-bit words have sane exponents; fp32 -> ~12% plausible.
__device__ __forceinline__ int detect_bf16(const void* wp) {
    const u16* w = (const u16*)wp;
    int cnt = 0;
    for (int i = 0; i < 64; ++i) {
        int e = (w[2 * i] >> 7) & 0xff;
        cnt += (e >= 100 && e <= 131) ? 1 : 0;
    }
    return cnt >= 40;
}

__device__ __forceinline__ void load8(const void* base, size_t idx, int isbf, float* f) {
    if (isbf) {
        uint4 v = *(const uint4*)((const u16*)base + idx);
        f[0] = bf2f(v.x & 0xffffu); f[1] = bf2f(v.x >> 16);
        f[2] = bf2f(v.y & 0xffffu); f[3] = bf2f(v.y >> 16);
        f[4] = bf2f(v.z & 0xffffu); f[5] = bf2f(v.z >> 16);
        f[6] = bf2f(v.w & 0xffffu); f[7] = bf2f(v.w >> 16);
    } else {
        const float* p = (const float*)base + idx;
        float4 a = *(const float4*)p;
        float4 b = *(const float4*)(p + 4);
        f[0] = a.x; f[1] = a.y; f[2] = a.z; f[3] = a.w;
        f[4] = b.x; f[5] = b.y; f[6] = b.z; f[7] = b.w;
    }
}
__device__ __forceinline__ float load1(const void* base, size_t idx, int isbf) {
    return isbf ? bf2f(((const u16*)base)[idx]) : ((const float*)base)[idx];
}

// ---------------- QKV projection GEMM (MFMA) ----------------
// grid (4, 128, 3), block 256.  C[m][n] = sum_k A[m][k] B[n][k] + bias.
// z=0: A=x(16384) B=wq -> Q bf16, d_out lead halves
// z=1: A=x       B=wk -> K bf16 rows at kbase/kstride
// z=2: A=wv(512) B=x  -> Vt[b][e][key] bf16 (coalesced transposed epilogue)
__global__ __launch_bounds__(256) void proj_mfma(
    const void* __restrict__ x,
    const void* __restrict__ wq, const void* __restrict__ bq,
    const void* __restrict__ wk, const void* __restrict__ bk,
    const void* __restrict__ wv, const void* __restrict__ bv,
    char* __restrict__ qout, u16* __restrict__ kbase, size_t kstride,
    u16* __restrict__ vtout)
{
    __shared__ u16 As[128][40];     // [m][k] pad 40 (80 B rows, 16B-aligned)
    __shared__ u16 Bs[128][40];

    const int z = blockIdx.z;
    const void* W    = (z == 0) ? wq : (z == 1) ? wk : wv;
    const void* bias = (z == 0) ? bq : (z == 1) ? bk : bv;
    const int isbf = detect_bf16(W);

    const int t = threadIdx.x;
    const int w = t >> 6, l = t & 63;
    const int lane15 = l & 15, quad = l >> 4;
    const int wmo = w * 32;

    const void* Abase; const void* Bbase; int Arow0, Brow0;
    if (z < 2) { Abase = x; Arow0 = blockIdx.y * 128; Bbase = W; Brow0 = blockIdx.x * 128; }
    else       { Abase = W; Arow0 = blockIdx.x * 128; Bbase = x; Brow0 = blockIdx.y * 128; }

    float4v acc[2][8];
#pragma unroll
    for (int mi = 0; mi < 2; ++mi)
#pragma unroll
        for (int ni = 0; ni < 8; ++ni) acc[mi][ni] = (float4v){0.f, 0.f, 0.f, 0.f};

    const int srow = t >> 1;            // 0..127
    const int scol = (t & 1) * 16;      // 0 / 16

    for (int kt = 0; kt < E_DIM; kt += 32) {
        float fa[16], fb[16];
        load8(Abase, (size_t)(Arow0 + srow) * E_DIM + kt + scol,     isbf, fa);
        load8(Abase, (size_t)(Arow0 + srow) * E_DIM + kt + scol + 8, isbf, fa + 8);
        load8(Bbase, (size_t)(Brow0 + srow) * E_DIM + kt + scol,     isbf, fb);
        load8(Bbase, (size_t)(Brow0 + srow) * E_DIM + kt + scol + 8, isbf, fb + 8);
        __syncthreads();
        union { u16 h[8]; uint4 v; } pk;
#pragma unroll
        for (int half = 0; half < 2; ++half) {
#pragma unroll
            for (int j = 0; j < 8; ++j) pk.h[j] = f2bf_bits(fa[half * 8 + j]);
            *(uint4*)&As[srow][scol + half * 8] = pk.v;
#pragma unroll
            for (int j = 0; j < 8; ++j) pk.h[j] = f2bf_bits(fb[half * 8 + j]);
            *(uint4*)&Bs[srow][scol + half * 8] = pk.v;
        }
        __syncthreads();

        short8 af0 = *(const short8*)&As[wmo + lane15][quad * 8];
        short8 af1 = *(const short8*)&As[wmo + 16 + lane15][quad * 8];
#pragma unroll
        for (int ni = 0; ni < 8; ++ni) {
            short8 bf8 = *(const short8*)&Bs[ni * 16 + lane15][quad * 8];
            acc[0][ni] = mfma16(af0, bf8, acc[0][ni]);
            acc[1][ni] = mfma16(af1, bf8, acc[1][ni]);
        }
    }

    // epilogue
    if (z < 2) {
        float bcol[8];
#pragma unroll
        for (int ni = 0; ni < 8; ++ni)
            bcol[ni] = load1(bias, Brow0 + ni * 16 + lane15, isbf);
#pragma unroll
        for (int mi = 0; mi < 2; ++mi)
#pragma unroll
            for (int ni = 0; ni < 8; ++ni)
#pragma unroll
                for (int r = 0; r < 4; ++r) {
                    const int row = Arow0 + wmo + mi * 16 + quad * 4 + r;
                    const int col = Brow0 + ni * 16 + lane15;
                    const u16 v = f2bf_bits(acc[mi][ni][r] + bcol[ni]);
                    if (z == 0) *(u16*)(qout + (size_t)row * 2048 + col * 2) = v;
                    else        kbase[(size_t)row * kstride + col] = v;
                }
    } else {
        float brow[2][4];
#pragma unroll
        for (int mi = 0; mi < 2; ++mi)
#pragma unroll
            for (int r = 0; r < 4; ++r)
                brow[mi][r] = load1(bias, Arow0 + wmo + mi * 16 + quad * 4 + r, isbf);
#pragma unroll
        for (int mi = 0; mi < 2; ++mi)
#pragma unroll
            for (int ni = 0; ni < 8; ++ni)
#pragma unroll
                for (int r = 0; r < 4; ++r) {
                    const int e   = Arow0 + wmo + mi * 16 + quad * 4 + r;  // 0..511
                    const int col = Brow0 + ni * 16 + lane15;              // token
                    const int b = col >> 11, keyb = col & 2047;
                    vtout[((size_t)b * E_DIM + e) * S_DIM + keyb] =
                        f2bf_bits(acc[mi][ni][r] + brow[mi][r]);
                }
    }
}

// ---------------- attention (MFMA flash) ----------------
// grid 512 (bid&7 = batch -> XCD-local K/Vt), block 256 (4 waves).
// wave w: QK^T S[32q][keys w*16..+15]; PV O[32q][e w*128..+127].
__global__ __launch_bounds__(256, 2) void attn_mfma(
    const char* __restrict__ qbase,          // d_out lead halves
    const u16* __restrict__ kbase, size_t kstride,
    const u16* __restrict__ vtbuf,           // [8][512][2048]
    const int* __restrict__ mask,
    float* __restrict__ outp)
{
    __shared__ u16 Ps[2][32][72];            // [q][key] pad 72 (144 B rows)
    __shared__ float lred[4][32];

    const int t = threadIdx.x;
    const int w = t >> 6, l = t & 63;
    const int lane15 = l & 15, quad = l >> 4;
    const int bid = blockIdx.x;
    const int b = bid & 7;
    const int q0 = (bid >> 3) * 32;
    const int ew0 = w * 128;

    // Q fragments: 2 m-tiles x 16 e-steps, straight from global
    short8 qf[2][16];
#pragma unroll
    for (int mi = 0; mi < 2; ++mi) {
        const char* qr = qbase + (size_t)(b * S_DIM + q0 + mi * 16 + lane15) * 2048;
#pragma unroll
        for (int s = 0; s < 16; ++s)
            qf[mi][s] = *(const short8*)(qr + (s * 32 + quad * 8) * 2);
    }

    float4v oacc[2][8];
#pragma unroll
    for (int mi = 0; mi < 2; ++mi)
#pragma unroll
        for (int ni = 0; ni < 8; ++ni) oacc[mi][ni] = (float4v){0.f, 0.f, 0.f, 0.f};
    float lacc[2][4] = {};

    for (int c = 0; c < 32; ++c) {
        const int kb = c * 64;

        // mask prefetch (8 values, coalesced 64B per 16 lanes)
        int mv[2][4];
#pragma unroll
        for (int mi = 0; mi < 2; ++mi)
#pragma unroll
            for (int r = 0; r < 4; ++r)
                mv[mi][r] = mask[(size_t)(b * S_DIM + q0 + mi * 16 + quad * 4 + r) * S_DIM
                                 + kb + w * 16 + lane15];

        // ---- QK^T ----
        float4v s0 = (float4v){0.f, 0.f, 0.f, 0.f};
        float4v s1 = (float4v){0.f, 0.f, 0.f, 0.f};
        const u16* krow = kbase + (size_t)(b * S_DIM + kb + w * 16 + lane15) * kstride;
#pragma unroll
        for (int s = 0; s < 16; ++s) {
            short8 kf = *(const short8*)(krow + s * 32 + quad * 8);
            s0 = mfma16(qf[0][s], kf, s0);
            s1 = mfma16(qf[1][s], kf, s1);
        }

        // ---- softmax (no max subtraction; masked -> 0) + P write ----
#pragma unroll
        for (int r = 0; r < 4; ++r) {
            float p0 = (mv[0][r] > 0) ? 0.f : __expf(s0[r] * SCALE);
            float p1 = (mv[1][r] > 0) ? 0.f : __expf(s1[r] * SCALE);
            u16 h0 = f2bf_bits(p0), h1 = f2bf_bits(p1);
            lacc[0][r] += bf2f(h0);       // accumulate the rounded value
            lacc[1][r] += bf2f(h1);
            Ps[c & 1][quad * 4 + r][w * 16 + lane15] = h0;
            Ps[c & 1][16 + quad * 4 + r][w * 16 + lane15] = h1;
        }
        __syncthreads();

        // ---- PV ----
#pragma unroll
        for (int ks = 0; ks < 2; ++ks) {
            short8 pf0 = *(const short8*)&Ps[c & 1][lane15][ks * 32 + quad * 8];
            short8 pf1 = *(const short8*)&Ps[c & 1][16 + lane15][ks * 32 + quad * 8];
#pragma unroll
            for (int ni = 0; ni < 8; ++ni) {
                const u16* vr = vtbuf + ((size_t)b * E_DIM + ew0 + ni * 16 + lane15) * S_DIM
                                + kb + ks * 32 + quad * 8;
                short8 vf = *(const short8*)vr;
                oacc[0][ni] = mfma16(pf0, vf, oacc[0][ni]);
                oacc[1][ni] = mfma16(pf1, vf, oacc[1][ni]);
            }
        }
    }

    // row-sum reduction: over 16 cols (shfl) then over 4 waves (LDS)
#pragma unroll
    for (int mi = 0; mi < 2; ++mi)
#pragma unroll
        for (int r = 0; r < 4; ++r) {
            float v = lacc[mi][r];
            v += __shfl_xor(v, 1, 64);
            v += __shfl_xor(v, 2, 64);
            v += __shfl_xor(v, 4, 64);
            v += __shfl_xor(v, 8, 64);
            if (lane15 == 0) lred[w][mi * 16 + quad * 4 + r] = v;
        }
    __syncthreads();

    float inv_[2][4];
#pragma unroll
    for (int mi = 0; mi < 2; ++mi)
#pragma unroll
        for (int r = 0; r < 4; ++r) {
            const int row = mi * 16 + quad * 4 + r;
            inv_[mi][r] = 1.f / (lred[0][row] + lred[1][row] + lred[2][row] + lred[3][row]);
        }

#pragma unroll
    for (int mi = 0; mi < 2; ++mi)
#pragma unroll
        for (int ni = 0; ni < 8; ++ni)
#pragma unroll
            for (int r = 0; r < 4; ++r)
                outp[(size_t)(b * S_DIM + q0 + mi * 16 + quad * 4 + r) * E_DIM
                     + ew0 + ni * 16 + lane15] = oacc[mi][ni][r] * inv_[mi][r];
}

extern "C" void kernel_launch(void* const* d_in, const int* in_sizes, int n_in,
                              void* d_out, int out_size, void* d_ws, size_t ws_size,
                              hipStream_t stream) {
    const void* x    = d_in[0];
    const int*  mask = (const int*)d_in[1];
    const void* wq   = d_in[2];
    const void* bq   = d_in[3];
    const void* wk   = d_in[4];
    const void* bk   = d_in[5];
    const void* wv   = d_in[6];
    const void* bv   = d_in[7];

    const size_t VT_BYTES = (size_t)8 * E_DIM * S_DIM * 2;   // 16.8 MB
    const int big = ws_size >= 2 * VT_BYTES;

    u16* vt = (u16*)d_ws;
    u16* kb_; size_t kstride;
    float* attn_out;
    if (big) {                       // K in d_ws, attention writes d_out
        kb_ = (u16*)((char*)d_ws + VT_BYTES);
        kstride = 512;
        attn_out = (float*)d_out;
    } else {                         // K in d_out trailing halves; out -> x; copy
        kb_ = (u16*)d_out + 512;
        kstride = 1024;
        attn_out = (float*)x;
    }

    dim3 gp(4, NROWS / 128, 3);
    proj_mfma<<<gp, 256, 0, stream>>>(x, wq, bq, wk, bk, wv, bv,
                                      (char*)d_out, kb_, kstride, vt);

    attn_mfma<<<512, 256, 0, stream>>>((const char*)d_out, kb_, kstride, vt,
                                       mask, attn_out);

    if (!big)
        hipMemcpyAsync(d_out, (void*)x, (size_t)NROWS * E_DIM * 4,
                       hipMemcpyDeviceToDevice, stream);
}

// Round 5
// 412.886 us; speedup vs baseline: 16.8069x; 1.3741x over previous
//
#include <hip/hip_runtime.h>
#include <hip/hip_bf16.h>

// MHAHead B=8,S=2048,E=512. R5: all-GEMM m97 structure.
//   conv_x: x fp32 -> bf16 in-place lead halves (stride 1024 u16); bf16 input: no-op (stride 512)
//   conv_w: weights/biases -> bf16 in ws
//   proj  : uni GEMM 128x128xBK32, global_load_lds(16B), XOR-swizzled LDS; z=2 computes Vt directly
//   gemmS : S = exp(mask? -inf : Q.K^T * scale) bf16  [8][2048][2048]
//   gemmO : out = (S @ Vt) / rowsum(S), rowsum via all-ones-B MFMA column

typedef unsigned short u16;
typedef __attribute__((ext_vector_type(8))) short short8;
typedef __attribute__((ext_vector_type(4))) float float4v;

#define S_DIM 2048
#define E_DIM 512
#define NROWS (8 * S_DIM)
#define SCALE 0.044194173824159216f

__device__ __forceinline__ float4v mfma16(short8 a, short8 b, float4v c) {
    return __builtin_amdgcn_mfma_f32_16x16x32_bf16(a, b, c, 0, 0, 0);
}
__device__ __forceinline__ float bf2f(unsigned int u) {
    union { unsigned int i; float f; } v; v.i = u << 16; return v.f;
}
__device__ __forceinline__ u16 f2bf_bits(float f) {
    __hip_bfloat16 h = __float2bfloat16(f);
    return *(u16*)&h;
}
__device__ __forceinline__ int detect_bf16(const void* wp) {
    const u16* w = (const u16*)wp;
    int cnt = 0;
    for (int i = 0; i < 64; ++i) {
        int e = (w[2 * i] >> 7) & 0xff;
        cnt += (e >= 100 && e <= 131) ? 1 : 0;
    }
    return cnt >= 40;
}
__device__ __forceinline__ void load8(const void* base, size_t idx, int isbf, float* f) {
    if (isbf) {
        uint4 v = *(const uint4*)((const u16*)base + idx);
        f[0] = bf2f(v.x & 0xffffu); f[1] = bf2f(v.x >> 16);
        f[2] = bf2f(v.y & 0xffffu); f[3] = bf2f(v.y >> 16);
        f[4] = bf2f(v.z & 0xffffu); f[5] = bf2f(v.z >> 16);
        f[6] = bf2f(v.w & 0xffffu); f[7] = bf2f(v.w >> 16);
    } else {
        const float* p = (const float*)base + idx;
        float4 a = *(const float4*)p;
        float4 b = *(const float4*)(p + 4);
        f[0] = a.x; f[1] = a.y; f[2] = a.z; f[3] = a.w;
        f[4] = b.x; f[5] = b.y; f[6] = b.z; f[7] = b.w;
    }
}
__device__ __forceinline__ float load1(const void* base, size_t idx, int isbf) {
    return isbf ? bf2f(((const u16*)base)[idx]) : ((const float*)base)[idx];
}

// async 16B global -> LDS (per-lane src, wave-uniform LDS base + lane*16)
__device__ __forceinline__ void gld16(const u16* g, u16* l) {
    __builtin_amdgcn_global_load_lds(
        (const __attribute__((address_space(1))) void*)g,
        (__attribute__((address_space(3))) void*)l, 16, 0, 0);
}

// ---------------- conversion kernels ----------------
// x fp32 -> bf16 into leading 1024B of each 2048B row (stride 1024 u16).
// One wave per row; all lane-reads complete before the wave's stores issue.
__global__ __launch_bounds__(256) void conv_x(void* xbuf, const void* wq_orig) {
    if (detect_bf16(wq_orig)) return;            // already bf16, dense stride 512
    const int w = threadIdx.x >> 6, l = threadIdx.x & 63;
    const int row = blockIdx.x * 4 + w;
    const float* src = (const float*)xbuf + (size_t)row * E_DIM + l * 8;
    float4 a = *(const float4*)src;
    float4 b = *(const float4*)(src + 4);
    union { u16 h[8]; uint4 v; } pk;
    pk.h[0] = f2bf_bits(a.x); pk.h[1] = f2bf_bits(a.y);
    pk.h[2] = f2bf_bits(a.z); pk.h[3] = f2bf_bits(a.w);
    pk.h[4] = f2bf_bits(b.x); pk.h[5] = f2bf_bits(b.y);
    pk.h[6] = f2bf_bits(b.z); pk.h[7] = f2bf_bits(b.w);
    *(uint4*)((u16*)xbuf + (size_t)row * 1024 + l * 8) = pk.v;
}

// weights [3][512][512] + biases [3][512] -> bf16 in ws
__global__ __launch_bounds__(256) void conv_w(
    const void* w0, const void* w1, const void* w2,
    const void* b0, const void* b1, const void* b2, u16* wb)
{
    const int z = blockIdx.y;
    const void* w = (z == 0) ? w0 : (z == 1) ? w1 : w2;
    const void* bb = (z == 0) ? b0 : (z == 1) ? b1 : b2;
    const int isbf = detect_bf16(w0);
    const size_t idx = ((size_t)blockIdx.x * 256 + threadIdx.x) * 8;
    float f[8];
    load8(w, idx, isbf, f);
    union { u16 h[8]; uint4 v; } pk;
#pragma unroll
    for (int j = 0; j < 8; ++j) pk.h[j] = f2bf_bits(f[j]);
    *(uint4*)(wb + (size_t)z * 262144 + idx) = pk.v;
    if (blockIdx.x == 0) {
        u16* bbase = wb + 3 * 262144 + z * 512;
#pragma unroll
        for (int j = 0; j < 2; ++j) {
            int i = threadIdx.x * 2 + j;
            bbase[i] = f2bf_bits(load1(bb, i, isbf));
        }
    }
}

// ---------------- shared GEMM core ----------------
// 128x128 tile, BK=32, 4 waves (2x2 of 64x64), m97 2-barrier K-loop.
// LDS layout: granule(16B) flat = 4*r + (kq ^ ((r>>1)&3))  -> 2-way max conflicts.
template<int ONES>
__device__ __forceinline__ void gemm_core(
    const u16* __restrict__ A, int sA, const u16* __restrict__ B, int sB, int K,
    u16* As, u16* Bs, float4v acc[4][4], float4v accS[4])
{
    const int t = threadIdx.x;
    const int w = t >> 6, l = t & 63;
    const int lane15 = l & 15, quad = l >> 4;
    const int wm = w & 1, wn = w >> 1;

    short8 ones;
#pragma unroll
    for (int j = 0; j < 8; ++j) ones[j] = (short)0x3F80;

    for (int kt = 0; kt < K; kt += 32) {
        __syncthreads();
#pragma unroll
        for (int i = 0; i < 2; ++i) {
            const int fg = w * 128 + i * 64 + l;
            const int r = fg >> 2;
            const int kq = (fg & 3) ^ ((r >> 1) & 3);
            gld16(A + (size_t)r * sA + kt + kq * 8, As + fg * 8);
            gld16(B + (size_t)r * sB + kt + kq * 8, Bs + fg * 8);
        }
        __syncthreads();

        short8 af[4], bf[4];
#pragma unroll
        for (int mi = 0; mi < 4; ++mi) {
            const int r = wm * 64 + mi * 16 + lane15;
            af[mi] = *(const short8*)&As[(4 * r + (quad ^ ((r >> 1) & 3))) * 8];
        }
#pragma unroll
        for (int ni = 0; ni < 4; ++ni) {
            const int r = wn * 64 + ni * 16 + lane15;
            bf[ni] = *(const short8*)&Bs[(4 * r + (quad ^ ((r >> 1) & 3))) * 8];
        }
#pragma unroll
        for (int mi = 0; mi < 4; ++mi) {
#pragma unroll
            for (int ni = 0; ni < 4; ++ni)
                acc[mi][ni] = mfma16(af[mi], bf[ni], acc[mi][ni]);
            if (ONES) accS[mi] = mfma16(af[mi], ones, accS[mi]);
        }
    }
}

#define GEMM_PRE()                                                     \
    __shared__ u16 As[4096] __attribute__((aligned(16)));              \
    __shared__ u16 Bs[4096] __attribute__((aligned(16)));              \
    const int t = threadIdx.x;                                         \
    const int w = t >> 6, l = t & 63;                                  \
    const int lane15 = l & 15, quad = l >> 4;                          \
    const int wm = w & 1, wn = w >> 1;                                 \
    (void)l;                                                           \
    float4v acc[4][4];                                                 \
    float4v accS[4];                                                   \
    _Pragma("unroll") for (int mi = 0; mi < 4; ++mi) {                 \
        accS[mi] = (float4v){0.f, 0.f, 0.f, 0.f};                      \
        _Pragma("unroll") for (int ni = 0; ni < 4; ++ni)               \
            acc[mi][ni] = (float4v){0.f, 0.f, 0.f, 0.f};               \
    }

// ---------------- proj: Q, K, Vt ----------------
// z<2: A = xb[m0..], B = wb[z][n0..]; z=2: A = wb[2][m0..], B = xb[n0..] (C = Vt)
__global__ __launch_bounds__(256) void proj_gemm(
    const void* __restrict__ xorig, const void* __restrict__ wq_orig,
    const u16* __restrict__ wb,
    u16* __restrict__ qb, u16* __restrict__ kb, int sQK, u16* __restrict__ vt)
{
    GEMM_PRE();
    const int z = blockIdx.z;
    const int isbf = detect_bf16(wq_orig);
    const u16* xb = (const u16*)xorig;
    const int sx = isbf ? 512 : 1024;
    const u16* bias = wb + 3 * 262144 + z * 512;

    int m0, n0; const u16 *A, *B; int sA, sB;
    if (z < 2) {
        m0 = blockIdx.y * 128; n0 = blockIdx.x * 128;
        A = xb + (size_t)m0 * sx; sA = sx;
        B = wb + (size_t)z * 262144 + (size_t)n0 * 512; sB = 512;
    } else {
        m0 = blockIdx.x * 128; n0 = blockIdx.y * 128;
        A = wb + (size_t)2 * 262144 + (size_t)m0 * 512; sA = 512;
        B = xb + (size_t)n0 * sx; sB = sx;
    }

    gemm_core<0>(A, sA, B, sB, 512, As, Bs, acc, accS);

    if (z < 2) {
        u16* dst = z ? kb : qb;
        float bcol[4];
#pragma unroll
        for (int ni = 0; ni < 4; ++ni)
            bcol[ni] = bf2f(bias[n0 + wn * 64 + ni * 16 + lane15]);
#pragma unroll
        for (int mi = 0; mi < 4; ++mi)
#pragma unroll
            for (int ni = 0; ni < 4; ++ni)
#pragma unroll
                for (int r = 0; r < 4; ++r) {
                    const int row = m0 + wm * 64 + mi * 16 + quad * 4 + r;
                    const int col = n0 + wn * 64 + ni * 16 + lane15;
                    dst[(size_t)row * sQK + col] = f2bf_bits(acc[mi][ni][r] + bcol[ni]);
                }
    } else {
#pragma unroll
        for (int mi = 0; mi < 4; ++mi)
#pragma unroll
            for (int r = 0; r < 4; ++r) {
                const int e = m0 + wm * 64 + mi * 16 + quad * 4 + r;      // 0..511
                const float bias_e = bf2f(bias[e]);
#pragma unroll
                for (int ni = 0; ni < 4; ++ni) {
                    const int tok = n0 + wn * 64 + ni * 16 + lane15;
                    vt[((size_t)(tok >> 11) * 512 + e) * 2048 + (tok & 2047)] =
                        f2bf_bits(acc[mi][ni][r] + bias_e);
                }
            }
    }
}

// ---------------- gemmS: S = exp(masked(Q.K^T * scale)) bf16 ----------------
__global__ __launch_bounds__(256) void gemmS(
    const u16* __restrict__ qb, const u16* __restrict__ kb, int sQK,
    const int* __restrict__ mask, u16* sx_base, u16* sws_base, int nx)
{
    GEMM_PRE();
    const int b = blockIdx.z;
    const int m0 = blockIdx.y * 128, n0 = blockIdx.x * 128;
    const u16* A = qb + (size_t)(b * S_DIM + m0) * sQK;
    const u16* B = kb + (size_t)(b * S_DIM + n0) * sQK;

    gemm_core<0>(A, sQK, B, sQK, 512, As, Bs, acc, accS);

    u16* Sb = (b < nx) ? (sx_base + (size_t)b * S_DIM * S_DIM)
                       : (sws_base + (size_t)(b - nx) * S_DIM * S_DIM);
#pragma unroll
    for (int mi = 0; mi < 4; ++mi)
#pragma unroll
        for (int r = 0; r < 4; ++r) {
            const int row = m0 + wm * 64 + mi * 16 + quad * 4 + r;
            const int col0 = n0 + wn * 64 + lane15;
            int mk[4];
#pragma unroll
            for (int ni = 0; ni < 4; ++ni)
                mk[ni] = mask[((size_t)b * S_DIM + row) * S_DIM + col0 + ni * 16];
#pragma unroll
            for (int ni = 0; ni < 4; ++ni) {
                const float p = (mk[ni] > 0) ? 0.f : __expf(acc[mi][ni][r] * SCALE);
                Sb[(size_t)row * S_DIM + col0 + ni * 16] = f2bf_bits(p);
            }
        }
}

// ---------------- gemmO: out = (S @ Vt) / rowsum(S) ----------------
__global__ __launch_bounds__(256) void gemmO(
    const u16* sx_base, const u16* sws_base, int nx,
    const u16* __restrict__ vt, float* __restrict__ outp)
{
    GEMM_PRE();
    const int b = blockIdx.z;
    const int m0 = blockIdx.y * 128, n0 = blockIdx.x * 128;
    const u16* Sb = (b < nx) ? (sx_base + (size_t)b * S_DIM * S_DIM)
                             : (sws_base + (size_t)(b - nx) * S_DIM * S_DIM);
    const u16* A = Sb + (size_t)m0 * S_DIM;
    const u16* B = vt + ((size_t)b * 512 + n0) * 2048;

    gemm_core<1>(A, S_DIM, B, S_DIM, S_DIM, As, Bs, acc, accS);

#pragma unroll
    for (int mi = 0; mi < 4; ++mi)
#pragma unroll
        for (int r = 0; r < 4; ++r) {
            const int row = m0 + wm * 64 + mi * 16 + quad * 4 + r;
            const float inv = 1.f / accS[mi][r];
#pragma unroll
            for (int ni = 0; ni < 4; ++ni) {
                const int col = n0 + wn * 64 + ni * 16 + lane15;
                outp[((size_t)b * S_DIM + row) * E_DIM + col] = acc[mi][ni][r] * inv;
            }
        }
}

extern "C" void kernel_launch(void* const* d_in, const int* in_sizes, int n_in,
                              void* d_out, int out_size, void* d_ws, size_t ws_size,
                              hipStream_t stream) {
    const void* x    = d_in[0];
    const int*  mask = (const int*)d_in[1];
    const void* wq   = d_in[2];
    const void* bq   = d_in[3];
    const void* wk   = d_in[4];
    const void* bk   = d_in[5];
    const void* wv   = d_in[6];
    const void* bv   = d_in[7];

    const size_t MB    = 1u << 20;
    const size_t QSZ   = (size_t)NROWS * E_DIM;         // u16 elems, 16.8 MB
    const size_t S_PB  = (size_t)S_DIM * S_DIM;         // u16 elems per batch
    const size_t BIG_NEED = 2 * MB + 3 * QSZ * 2 + 8 * S_PB * 2;   // ~119.5 MB

    u16* wb = (u16*)d_ws;                               // 2 MB region
    u16 *qb, *kb, *vtb, *sws;
    u16* sx_base = (u16*)x;
    int sQK, nx;
    if (ws_size >= BIG_NEED) {
        qb  = (u16*)((char*)d_ws + 2 * MB);
        kb  = qb + QSZ;
        vtb = kb + QSZ;
        sws = vtb + QSZ;
        sQK = 512; nx = 0;
    } else {
        qb  = (u16*)d_out;                              // lead halves
        kb  = (u16*)d_out + 512;                        // trail halves
        vtb = (u16*)((char*)d_ws + 2 * MB);
        sws = vtb + QSZ;
        sQK = 1024; nx = 2;                             // 2 S-batches over dead x
    }

    conv_w<<<dim3(128, 3), 256, 0, stream>>>(wq, wk, wv, bq, bk, bv, wb);
    conv_x<<<NROWS / 4, 256, 0, stream>>>((void*)x, wq);

    proj_gemm<<<dim3(4, 128, 3), 256, 0, stream>>>(x, wq, wb, qb, kb, sQK, vtb);

    gemmS<<<dim3(16, 16, 8), 256, 0, stream>>>(qb, kb, sQK, mask,
                                               sx_base, sws, nx);

    gemmO<<<dim3(4, 16, 8), 256, 0, stream>>>(sx_base, sws, nx, vtb,
                                              (float*)d_out);
}